// Round 1
// baseline (3240.651 us; speedup 1.0000x reference)
//
#include <hip/hip_runtime.h>
#include <hip/hip_bf16.h>

#define D 128
#define NPB 2

// ---- float atomic-max via monotonic uint mapping (memset-0 == -inf identity)
__device__ __forceinline__ unsigned flipf(float f) {
    unsigned u = __float_as_uint(f);
    return (u & 0x80000000u) ? ~u : (u | 0x80000000u);
}
__device__ __forceinline__ float unflipf(unsigned u) {
    unsigned v = (u & 0x80000000u) ? (u ^ 0x80000000u) : ~u;
    return __uint_as_float(v);
}

__global__ __launch_bounds__(256) void k_segmax(const int* __restrict__ tgt,
                                                const float* __restrict__ ew,
                                                unsigned* __restrict__ mflip, int E) {
    int i = blockIdx.x * blockDim.x + threadIdx.x;
    int stride = gridDim.x * blockDim.x;
    for (int e = i; e < E; e += stride)
        atomicMax(&mflip[tgt[e]], flipf(ew[e]));
}

__global__ __launch_bounds__(256) void k_expsum(const int* __restrict__ tgt,
                                                const float* __restrict__ w,
                                                const unsigned* __restrict__ mflip,
                                                float* __restrict__ ewbuf,
                                                float* __restrict__ denom, int E) {
    int i = blockIdx.x * blockDim.x + threadIdx.x;
    int stride = gridDim.x * blockDim.x;
    for (int e = i; e < E; e += stride) {
        int t = tgt[e];
        float v = expf(w[e] - unflipf(mflip[t]));
        ewbuf[e] = v;
        unsafeAtomicAdd(&denom[t], v);
    }
}

// 32 threads per edge; each thread does one float4 slice of D=128.
__global__ __launch_bounds__(256) void k_scatter(const int* __restrict__ src,
                                                 const int* __restrict__ tgt,
                                                 const float* __restrict__ x,
                                                 const float* __restrict__ ewbuf,
                                                 const float* __restrict__ denom,
                                                 float* __restrict__ agg, int E) {
    int t = blockIdx.x * blockDim.x + threadIdx.x;
    int total = E * 32;
    if (t >= total) return;
    int e = t >> 5;
    int k = t & 31;
    int tg = tgt[e];
    float wgt = ewbuf[e] / denom[tg];
    const float4 xv = reinterpret_cast<const float4*>(x + (size_t)src[e] * D)[k];
    float* ap = agg + (size_t)tg * D + k * 4;
    unsafeAtomicAdd(ap + 0, wgt * xv.x);
    unsafeAtomicAdd(ap + 1, wgt * xv.y);
    unsafeAtomicAdd(ap + 2, wgt * xv.z);
    unsafeAtomicAdd(ap + 3, wgt * xv.w);
}

// One 128-thread group per node; NPB nodes per block.
__global__ __launch_bounds__(NPB * 128) void k_node(
    const float* __restrict__ x, const float* __restrict__ agg,
    const float* __restrict__ W1, const float* __restrict__ b1,
    const float* __restrict__ W2, const float* __restrict__ b2,
    const float* __restrict__ gamma, const float* __restrict__ beta,
    float* __restrict__ out, int n)
{
    int g  = threadIdx.x >> 7;
    int lt = threadIdx.x & 127;
    int node = blockIdx.x * NPB + g;
    if (node >= n) node = n - 1;   // tail clamp (benign duplicate work)

    __shared__ float sh[NPB][D];
    __shared__ float r0[NPB][2], r1[NPB][2];

    // projective average: normalize agg row to unit sphere
    float a = agg[(size_t)node * D + lt];
    float ss = a * a;
    #pragma unroll
    for (int o = 32; o; o >>= 1) ss += __shfl_down(ss, o);
    if ((lt & 63) == 0) r0[g][lt >> 6] = ss;
    __syncthreads();
    float nrm = sqrtf(r0[g][0] + r0[g][1]);
    float neigh = a / (nrm + 1e-9f);
    float comb = x[(size_t)node * D + lt] + neigh;   // (1+eps_gin)*x + neigh, eps=0
    __syncthreads();
    sh[g][lt] = comb;
    __syncthreads();

    // GEMV1 + ReLU
    float acc = b1[lt];
    #pragma unroll 8
    for (int i = 0; i < D; ++i)
        acc = fmaf(sh[g][i], W1[i * D + lt], acc);
    float h1 = fmaxf(acc, 0.f);
    __syncthreads();
    sh[g][lt] = h1;
    __syncthreads();

    // GEMV2
    float acc2 = b2[lt];
    #pragma unroll 8
    for (int i = 0; i < D; ++i)
        acc2 = fmaf(sh[g][i], W2[i * D + lt], acc2);

    // LayerNorm across D
    float s1 = acc2, s2 = acc2 * acc2;
    #pragma unroll
    for (int o = 32; o; o >>= 1) { s1 += __shfl_down(s1, o); s2 += __shfl_down(s2, o); }
    if ((lt & 63) == 0) { r0[g][lt >> 6] = s1; r1[g][lt >> 6] = s2; }
    __syncthreads();
    float mu  = (r0[g][0] + r0[g][1]) * (1.f / D);
    float var = (r1[g][0] + r1[g][1]) * (1.f / D) - mu * mu;
    float y = gamma[lt] * (acc2 - mu) * rsqrtf(var + 1e-5f) + beta[lt];
    out[(size_t)node * D + lt] = y;
}

extern "C" void kernel_launch(void* const* d_in, const int* in_sizes, int n_in,
                              void* d_out, int out_size, void* d_ws, size_t ws_size,
                              hipStream_t stream) {
    const float* x     = (const float*)d_in[0];
    const int*   ei    = (const int*)d_in[1];
    const float* ew    = (const float*)d_in[2];
    const float* W1    = (const float*)d_in[3];
    const float* b1    = (const float*)d_in[4];
    const float* W2    = (const float*)d_in[5];
    const float* b2    = (const float*)d_in[6];
    const float* gamma = (const float*)d_in[7];
    const float* beta  = (const float*)d_in[8];

    int n = in_sizes[0] / D;
    int E = in_sizes[2];
    const int* src = ei;
    const int* tgt = ei + E;

    char* ws = (char*)d_ws;
    float*    agg   = (float*)ws;    ws += (size_t)n * D * sizeof(float);
    unsigned* mflip = (unsigned*)ws; ws += (size_t)n * sizeof(unsigned);
    float*    denom = (float*)ws;    ws += (size_t)n * sizeof(float);
    float*    ewbuf = (float*)ws;    ws += (size_t)E * sizeof(float);

    // zero agg + mflip + denom in one contiguous memset (0 bits == identity for all three)
    size_t zbytes = (size_t)n * D * sizeof(float) + 2 * (size_t)n * sizeof(float);
    hipMemsetAsync((void*)agg, 0, zbytes, stream);

    k_segmax<<<2048, 256, 0, stream>>>(tgt, ew, mflip, E);
    k_expsum<<<2048, 256, 0, stream>>>(tgt, ew, mflip, ewbuf, denom, E);

    int totalScatter = E * 32;
    k_scatter<<<(totalScatter + 255) / 256, 256, 0, stream>>>(src, tgt, x, ewbuf, denom, agg, E);

    k_node<<<(n + NPB - 1) / NPB, NPB * 128, 0, stream>>>(
        x, agg, W1, b1, W2, b2, gamma, beta, (float*)d_out, n);
}

// Round 2
// 681.237 us; speedup vs baseline: 4.7570x; 4.7570x over previous
//
#include <hip/hip_runtime.h>
#include <hip/hip_bf16.h>

#define D 128
#define NPB 2
#define SCAN_T 256
#define SCAN_I 4
#define SCAN_CHUNK (SCAN_T * SCAN_I)

// ---------- CSR build ----------
__global__ __launch_bounds__(256) void k_hist(const int* __restrict__ tgt,
                                              int* __restrict__ deg, int E) {
    int i = blockIdx.x * blockDim.x + threadIdx.x;
    int stride = gridDim.x * blockDim.x;
    for (int e = i; e < E; e += stride) atomicAdd(&deg[tgt[e]], 1);
}

__global__ __launch_bounds__(SCAN_T) void k_scan_local(const int* __restrict__ deg,
                                                       int* __restrict__ rowptr,
                                                       int* __restrict__ part, int n) {
    __shared__ int sh[SCAN_T];
    int base = blockIdx.x * SCAN_CHUNK + threadIdx.x * SCAN_I;
    int v[SCAN_I]; int tsum = 0;
    #pragma unroll
    for (int k = 0; k < SCAN_I; ++k) { int idx = base + k; v[k] = (idx < n) ? deg[idx] : 0; tsum += v[k]; }
    sh[threadIdx.x] = tsum; __syncthreads();
    for (int off = 1; off < SCAN_T; off <<= 1) {
        int o = (threadIdx.x >= (unsigned)off) ? sh[threadIdx.x - off] : 0;
        __syncthreads();
        sh[threadIdx.x] += o;
        __syncthreads();
    }
    int excl = sh[threadIdx.x] - tsum;
    #pragma unroll
    for (int k = 0; k < SCAN_I; ++k) { int idx = base + k; if (idx < n) rowptr[idx] = excl; excl += v[k]; }
    if (threadIdx.x == 0) part[blockIdx.x] = sh[SCAN_T - 1];
}

// nblk must be <= SCAN_T (n up to 262144 — here n=100000 -> nblk=98)
__global__ __launch_bounds__(SCAN_T) void k_scan_mid(int* part, int nblk) {
    __shared__ int sh[SCAN_T];
    int v = (threadIdx.x < (unsigned)nblk) ? part[threadIdx.x] : 0;
    sh[threadIdx.x] = v; __syncthreads();
    for (int off = 1; off < SCAN_T; off <<= 1) {
        int o = (threadIdx.x >= (unsigned)off) ? sh[threadIdx.x - off] : 0;
        __syncthreads();
        sh[threadIdx.x] += o;
        __syncthreads();
    }
    if (threadIdx.x < (unsigned)nblk) part[threadIdx.x] = sh[threadIdx.x] - v;  // exclusive
}

__global__ __launch_bounds__(256) void k_scan_add(int* __restrict__ rowptr,
                                                  int* __restrict__ cursor,
                                                  const int* __restrict__ part, int n, int E) {
    int i = blockIdx.x * blockDim.x + threadIdx.x;
    if (i < n) { int r = rowptr[i] + part[i / SCAN_CHUNK]; rowptr[i] = r; cursor[i] = r; }
    if (i == n) rowptr[n] = E;
}

__global__ __launch_bounds__(256) void k_reorder(const int* __restrict__ src,
                                                 const int* __restrict__ tgt,
                                                 const float* __restrict__ ew,
                                                 int* __restrict__ cursor,
                                                 int2* __restrict__ csr, int E) {
    int i = blockIdx.x * blockDim.x + threadIdx.x;
    int stride = gridDim.x * blockDim.x;
    for (int e = i; e < E; e += stride) {
        int t = tgt[e];
        int pos = atomicAdd(&cursor[t], 1);
        csr[pos] = make_int2(src[e], __float_as_int(ew[e]));
    }
}

// ---------- fused: softmax-agg + sphere-norm + MLP + LN, one 128-group per node ----------
__global__ __launch_bounds__(NPB * 128) void k_fused(
    const int* __restrict__ rowptr, const int2* __restrict__ csr,
    const float* __restrict__ x,
    const float* __restrict__ W1, const float* __restrict__ b1,
    const float* __restrict__ W2, const float* __restrict__ b2,
    const float* __restrict__ gamma, const float* __restrict__ beta,
    float* __restrict__ out, int n)
{
    int g  = threadIdx.x >> 7;
    int lt = threadIdx.x & 127;
    int node = blockIdx.x * NPB + g;
    if (node >= n) node = n - 1;   // benign duplicate on tail

    __shared__ float sh[NPB][D];
    __shared__ float ra[NPB][2];

    int r0 = rowptr[node], r1 = rowptr[node + 1];

    // --- per-node softmax max ---
    float m = -INFINITY;
    for (int e = r0 + lt; e < r1; e += 128) m = fmaxf(m, __int_as_float(csr[e].y));
    #pragma unroll
    for (int o = 32; o; o >>= 1) m = fmaxf(m, __shfl_down(m, o));
    if ((lt & 63) == 0) ra[g][lt >> 6] = m;
    __syncthreads();
    m = fmaxf(ra[g][0], ra[g][1]);
    __syncthreads();

    // --- sum of exp ---
    float s = 0.f;
    for (int e = r0 + lt; e < r1; e += 128) s += __expf(__int_as_float(csr[e].y) - m);
    #pragma unroll
    for (int o = 32; o; o >>= 1) s += __shfl_down(s, o);
    if ((lt & 63) == 0) ra[g][lt >> 6] = s;
    __syncthreads();
    s = ra[g][0] + ra[g][1];
    float inv = (s > 0.f) ? (1.f / s) : 0.f;
    __syncthreads();

    // --- weighted gather: acc[lt] = sum_e wn_e * x[src_e][lt] ---
    float acc = 0.f;
    int e = r0;
    for (; e + 4 <= r1; e += 4) {
        int2 c0 = csr[e + 0], c1 = csr[e + 1], c2 = csr[e + 2], c3 = csr[e + 3];
        float w0 = __expf(__int_as_float(c0.y) - m) * inv;
        float w1v = __expf(__int_as_float(c1.y) - m) * inv;
        float w2v = __expf(__int_as_float(c2.y) - m) * inv;
        float w3v = __expf(__int_as_float(c3.y) - m) * inv;
        float x0 = x[(size_t)c0.x * D + lt];
        float x1 = x[(size_t)c1.x * D + lt];
        float x2 = x[(size_t)c2.x * D + lt];
        float x3 = x[(size_t)c3.x * D + lt];
        acc = fmaf(w0, x0, acc);
        acc = fmaf(w1v, x1, acc);
        acc = fmaf(w2v, x2, acc);
        acc = fmaf(w3v, x3, acc);
    }
    for (; e < r1; ++e) {
        int2 c = csr[e];
        float wn = __expf(__int_as_float(c.y) - m) * inv;
        acc = fmaf(wn, x[(size_t)c.x * D + lt], acc);
    }

    // --- projective average: normalize to unit sphere ---
    float ss = acc * acc;
    #pragma unroll
    for (int o = 32; o; o >>= 1) ss += __shfl_down(ss, o);
    if ((lt & 63) == 0) ra[g][lt >> 6] = ss;
    __syncthreads();
    float nrm = sqrtf(ra[g][0] + ra[g][1]);
    float neigh = acc / (nrm + 1e-9f);
    float comb = x[(size_t)node * D + lt] + neigh;   // (1+eps)*x + neigh, eps=0
    __syncthreads();
    sh[g][lt] = comb;
    __syncthreads();

    // --- GEMV1 + ReLU ---
    float a1 = b1[lt];
    #pragma unroll 8
    for (int i = 0; i < D; ++i)
        a1 = fmaf(sh[g][i], W1[i * D + lt], a1);
    float h1 = fmaxf(a1, 0.f);
    __syncthreads();
    sh[g][lt] = h1;
    __syncthreads();

    // --- GEMV2 ---
    float a2 = b2[lt];
    #pragma unroll 8
    for (int i = 0; i < D; ++i)
        a2 = fmaf(sh[g][i], W2[i * D + lt], a2);

    // --- LayerNorm ---
    float s1 = a2, s2 = a2 * a2;
    __shared__ float rb[NPB][2];
    #pragma unroll
    for (int o = 32; o; o >>= 1) { s1 += __shfl_down(s1, o); s2 += __shfl_down(s2, o); }
    if ((lt & 63) == 0) { ra[g][lt >> 6] = s1; rb[g][lt >> 6] = s2; }
    __syncthreads();
    float mu  = (ra[g][0] + ra[g][1]) * (1.f / D);
    float var = (rb[g][0] + rb[g][1]) * (1.f / D) - mu * mu;
    float y = gamma[lt] * (a2 - mu) * rsqrtf(var + 1e-5f) + beta[lt];
    out[(size_t)node * D + lt] = y;
}

extern "C" void kernel_launch(void* const* d_in, const int* in_sizes, int n_in,
                              void* d_out, int out_size, void* d_ws, size_t ws_size,
                              hipStream_t stream) {
    const float* x     = (const float*)d_in[0];
    const int*   ei    = (const int*)d_in[1];
    const float* ew    = (const float*)d_in[2];
    const float* W1    = (const float*)d_in[3];
    const float* b1    = (const float*)d_in[4];
    const float* W2    = (const float*)d_in[5];
    const float* b2    = (const float*)d_in[6];
    const float* gamma = (const float*)d_in[7];
    const float* beta  = (const float*)d_in[8];

    int n = in_sizes[0] / D;
    int E = in_sizes[2];
    const int* src = ei;
    const int* tgt = ei + E;

    // workspace layout (csr first for 8B alignment)
    char* ws = (char*)d_ws;
    int2* csr    = (int2*)ws;  ws += (size_t)E * sizeof(int2);
    int*  deg    = (int*)ws;   ws += (size_t)n * sizeof(int);
    int*  rowptr = (int*)ws;   ws += ((size_t)n + 1) * sizeof(int);
    int*  cursor = (int*)ws;   ws += (size_t)n * sizeof(int);
    int*  part   = (int*)ws;   ws += (size_t)SCAN_T * sizeof(int);

    hipMemsetAsync((void*)deg, 0, (size_t)n * sizeof(int), stream);

    k_hist<<<2048, 256, 0, stream>>>(tgt, deg, E);

    int nblk = (n + SCAN_CHUNK - 1) / SCAN_CHUNK;   // 98 for n=100000 (must be <= 256)
    k_scan_local<<<nblk, SCAN_T, 0, stream>>>(deg, rowptr, part, n);
    k_scan_mid<<<1, SCAN_T, 0, stream>>>(part, nblk);
    k_scan_add<<<(n + 256) / 256, 256, 0, stream>>>(rowptr, cursor, part, n, E);

    k_reorder<<<2048, 256, 0, stream>>>(src, tgt, ew, cursor, csr, E);

    k_fused<<<(n + NPB - 1) / NPB, NPB * 128, 0, stream>>>(
        rowptr, csr, x, W1, b1, W2, b2, gamma, beta, (float*)d_out, n);
}

// Round 3
// 328.734 us; speedup vs baseline: 9.8580x; 2.0723x over previous
//
#include <hip/hip_runtime.h>
#include <hip/hip_bf16.h>

#define D 128
#define SCAN_T 256
#define SCAN_I 4
#define SCAN_CHUNK (SCAN_T * SCAN_I)

typedef __attribute__((ext_vector_type(8))) short short8;
typedef __attribute__((ext_vector_type(4))) float f32x4;

__device__ __forceinline__ unsigned short us_bf16(float f) {
    return __bfloat16_as_ushort(__float2bfloat16(f));
}
__device__ __forceinline__ unsigned pack_bf16(float a, float b) {
    return (unsigned)us_bf16(a) | ((unsigned)us_bf16(b) << 16);
}
__device__ __forceinline__ float bf_lo(unsigned v) { return __uint_as_float(v << 16); }
__device__ __forceinline__ float bf_hi(unsigned v) { return __uint_as_float(v & 0xffff0000u); }

// ---------- prep: x -> bf16 pairs; W -> bf16 transposed ----------
__global__ __launch_bounds__(256) void k_prepx(const float* __restrict__ x,
                                               unsigned* __restrict__ xb, int nf4) {
    int i = blockIdx.x * blockDim.x + threadIdx.x;
    if (i < nf4) {
        float4 v = reinterpret_cast<const float4*>(x)[i];
        uint2 o;
        o.x = pack_bf16(v.x, v.y);
        o.y = pack_bf16(v.z, v.w);
        reinterpret_cast<uint2*>(xb)[i] = o;
    }
}

__global__ __launch_bounds__(256) void k_prepw(const float* __restrict__ W1,
                                               const float* __restrict__ W2,
                                               unsigned short* __restrict__ W1t,
                                               unsigned short* __restrict__ W2t) {
    int idx = blockIdx.x * blockDim.x + threadIdx.x;   // 0..16383
    int k = idx >> 7, nn = idx & 127;
    W1t[nn * 128 + k] = us_bf16(W1[idx]);
    W2t[nn * 128 + k] = us_bf16(W2[idx]);
}

// ---------- CSR build ----------
__global__ __launch_bounds__(256) void k_hist(const int* __restrict__ tgt,
                                              int* __restrict__ deg, int E) {
    int i = blockIdx.x * blockDim.x + threadIdx.x;
    int stride = gridDim.x * blockDim.x;
    for (int e = i; e < E; e += stride) atomicAdd(&deg[tgt[e]], 1);
}

__global__ __launch_bounds__(SCAN_T) void k_scan_local(const int* __restrict__ deg,
                                                       int* __restrict__ rowptr,
                                                       int* __restrict__ part, int n) {
    __shared__ int sh[SCAN_T];
    int base = blockIdx.x * SCAN_CHUNK + threadIdx.x * SCAN_I;
    int v[SCAN_I]; int tsum = 0;
    #pragma unroll
    for (int k = 0; k < SCAN_I; ++k) { int idx = base + k; v[k] = (idx < n) ? deg[idx] : 0; tsum += v[k]; }
    sh[threadIdx.x] = tsum; __syncthreads();
    for (int off = 1; off < SCAN_T; off <<= 1) {
        int o = (threadIdx.x >= (unsigned)off) ? sh[threadIdx.x - off] : 0;
        __syncthreads();
        sh[threadIdx.x] += o;
        __syncthreads();
    }
    int excl = sh[threadIdx.x] - tsum;
    #pragma unroll
    for (int k = 0; k < SCAN_I; ++k) { int idx = base + k; if (idx < n) rowptr[idx] = excl; excl += v[k]; }
    if (threadIdx.x == 0) part[blockIdx.x] = sh[SCAN_T - 1];
}

__global__ __launch_bounds__(SCAN_T) void k_scan_mid(int* part, int nblk) {
    __shared__ int sh[SCAN_T];
    int v = (threadIdx.x < (unsigned)nblk) ? part[threadIdx.x] : 0;
    sh[threadIdx.x] = v; __syncthreads();
    for (int off = 1; off < SCAN_T; off <<= 1) {
        int o = (threadIdx.x >= (unsigned)off) ? sh[threadIdx.x - off] : 0;
        __syncthreads();
        sh[threadIdx.x] += o;
        __syncthreads();
    }
    if (threadIdx.x < (unsigned)nblk) part[threadIdx.x] = sh[threadIdx.x] - v;
}

__global__ __launch_bounds__(256) void k_scan_add(int* __restrict__ rowptr,
                                                  int* __restrict__ cursor,
                                                  const int* __restrict__ part, int n, int E) {
    int i = blockIdx.x * blockDim.x + threadIdx.x;
    if (i < n) { int r = rowptr[i] + part[i / SCAN_CHUNK]; rowptr[i] = r; cursor[i] = r; }
    if (i == n) rowptr[n] = E;
}

__global__ __launch_bounds__(256) void k_reorder(const int* __restrict__ src,
                                                 const int* __restrict__ tgt,
                                                 const float* __restrict__ ew,
                                                 int* __restrict__ cursor,
                                                 int2* __restrict__ csr, int E) {
    int i = blockIdx.x * blockDim.x + threadIdx.x;
    int stride = gridDim.x * blockDim.x;
    for (int e = i; e < E; e += stride) {
        int t = tgt[e];
        int pos = atomicAdd(&cursor[t], 1);
        csr[pos] = make_int2(src[e], __float_as_int(ew[e]));
    }
}

// ---------- aggregate: 1 wave per node; softmax + bf16 gather + sphere-norm ----------
__global__ __launch_bounds__(256) void k_agg(
    const int* __restrict__ rowptr, const int2* __restrict__ csr,
    const float* __restrict__ x, const unsigned* __restrict__ xb,
    unsigned* __restrict__ cmb, int n)
{
    int w = threadIdx.x >> 6;
    int lane = threadIdx.x & 63;
    int node = blockIdx.x * 4 + w;
    if (node >= n) node = n - 1;   // benign duplicate on tail

    int r0 = rowptr[node], r1 = rowptr[node + 1];

    // softmax max (lane-parallel over edges)
    float m = -INFINITY;
    for (int c = r0; c < r1; c += 64) {
        int e = c + lane;
        if (e < r1) m = fmaxf(m, __int_as_float(csr[e].y));
    }
    #pragma unroll
    for (int off = 32; off; off >>= 1) m = fmaxf(m, __shfl_xor(m, off));

    // softmax denom
    float s = 0.f;
    for (int c = r0; c < r1; c += 64) {
        int e = c + lane;
        if (e < r1) s += __expf(__int_as_float(csr[e].y) - m);
    }
    #pragma unroll
    for (int off = 32; off; off >>= 1) s += __shfl_xor(s, off);
    float inv = (s > 0.f) ? (1.f / s) : 0.f;

    // weighted gather: each lane owns dims {2*lane, 2*lane+1}
    float ax = 0.f, ay = 0.f;
    for (int c = r0; c < r1; c += 64) {
        int e = c + lane;
        int2 cr = (e < r1) ? csr[e] : make_int2(0, 0);
        float wn = (e < r1) ? __expf(__int_as_float(cr.y) - m) * inv : 0.f;
        int cnt = min(64, r1 - c);
        int j = 0;
        for (; j + 4 <= cnt; j += 4) {
            float w0 = __shfl(wn, j),     w1 = __shfl(wn, j + 1);
            float w2 = __shfl(wn, j + 2), w3 = __shfl(wn, j + 3);
            int  s0 = __shfl(cr.x, j),     s1 = __shfl(cr.x, j + 1);
            int  s2 = __shfl(cr.x, j + 2), s3 = __shfl(cr.x, j + 3);
            unsigned v0 = xb[(size_t)s0 * 64 + lane];
            unsigned v1 = xb[(size_t)s1 * 64 + lane];
            unsigned v2 = xb[(size_t)s2 * 64 + lane];
            unsigned v3 = xb[(size_t)s3 * 64 + lane];
            ax = fmaf(w0, bf_lo(v0), ax); ay = fmaf(w0, bf_hi(v0), ay);
            ax = fmaf(w1, bf_lo(v1), ax); ay = fmaf(w1, bf_hi(v1), ay);
            ax = fmaf(w2, bf_lo(v2), ax); ay = fmaf(w2, bf_hi(v2), ay);
            ax = fmaf(w3, bf_lo(v3), ax); ay = fmaf(w3, bf_hi(v3), ay);
        }
        for (; j < cnt; ++j) {
            float wj = __shfl(wn, j);
            int   sj = __shfl(cr.x, j);
            unsigned v = xb[(size_t)sj * 64 + lane];
            ax = fmaf(wj, bf_lo(v), ax);
            ay = fmaf(wj, bf_hi(v), ay);
        }
    }

    // projective average + combined = x + neigh
    float ss = ax * ax + ay * ay;
    #pragma unroll
    for (int off = 32; off; off >>= 1) ss += __shfl_xor(ss, off);
    float rn = 1.f / (sqrtf(ss) + 1e-9f);
    float2 xv = reinterpret_cast<const float2*>(x)[(size_t)node * 64 + lane];
    float cx = xv.x + ax * rn;
    float cy = xv.y + ay * rn;
    cmb[(size_t)node * 64 + lane] = pack_bf16(cx, cy);
}

// ---------- MLP + LN via MFMA: 64 nodes per block, 4 waves ----------
__global__ __launch_bounds__(256) void k_mlp(
    const unsigned* __restrict__ cmb,
    const unsigned short* __restrict__ W1t, const unsigned short* __restrict__ W2t,
    const float* __restrict__ b1, const float* __restrict__ b2,
    const float* __restrict__ gamma, const float* __restrict__ beta,
    float* __restrict__ out, int n)
{
    __shared__ __align__(16) unsigned short sA[64][136];
    __shared__ __align__(16) unsigned short sW[128][136];

    int node0 = blockIdx.x * 64;
    int w = threadIdx.x >> 6;
    int lane = threadIdx.x & 63;
    int lr = lane & 15;    // fragment row/col
    int lg = lane >> 4;    // k-group
    int mr = w * 16;       // this wave's row base in the tile

    // stage combined tile (bf16) and W1t
    for (int idx = threadIdx.x; idx < 64 * 16; idx += 256) {
        int row = idx >> 4, seg = idx & 15;
        int gr = node0 + row; if (gr >= n) gr = n - 1;
        uint4 v = reinterpret_cast<const uint4*>(cmb)[(size_t)gr * 16 + seg];
        *reinterpret_cast<uint4*>(&sA[row][seg * 8]) = v;
    }
    for (int idx = threadIdx.x; idx < 128 * 16; idx += 256) {
        int row = idx >> 4, seg = idx & 15;
        uint4 v = reinterpret_cast<const uint4*>(W1t)[row * 16 + seg];
        *reinterpret_cast<uint4*>(&sW[row][seg * 8]) = v;
    }
    __syncthreads();

    // GEMM1: h = relu(cmb @ W1 + b1), write back to sA as bf16
    short8 aF[4];
    #pragma unroll
    for (int kt = 0; kt < 4; ++kt)
        aF[kt] = *reinterpret_cast<const short8*>(&sA[mr + lr][kt * 32 + lg * 8]);

    #pragma unroll
    for (int nt = 0; nt < 8; ++nt) {
        f32x4 c = {0.f, 0.f, 0.f, 0.f};
        #pragma unroll
        for (int kt = 0; kt < 4; ++kt) {
            short8 bF = *reinterpret_cast<const short8*>(&sW[nt * 16 + lr][kt * 32 + lg * 8]);
            c = __builtin_amdgcn_mfma_f32_16x16x32_bf16(aF[kt], bF, c, 0, 0, 0);
        }
        float b1v = b1[nt * 16 + lr];
        #pragma unroll
        for (int reg = 0; reg < 4; ++reg) {
            float h = fmaxf(c[reg] + b1v, 0.f);
            sA[mr + lg * 4 + reg][nt * 16 + lr] = us_bf16(h);
        }
    }
    __syncthreads();

    // restage sW with W2t
    for (int idx = threadIdx.x; idx < 128 * 16; idx += 256) {
        int row = idx >> 4, seg = idx & 15;
        uint4 v = reinterpret_cast<const uint4*>(W2t)[row * 16 + seg];
        *reinterpret_cast<uint4*>(&sW[row][seg * 8]) = v;
    }
    __syncthreads();

    // GEMM2: a2 = h @ W2 + b2, then LayerNorm
    short8 a2F[4];
    #pragma unroll
    for (int kt = 0; kt < 4; ++kt)
        a2F[kt] = *reinterpret_cast<const short8*>(&sA[mr + lr][kt * 32 + lg * 8]);

    f32x4 c2[8];
    float b2v[8], gv[8], bev[8];
    #pragma unroll
    for (int nt = 0; nt < 8; ++nt) {
        c2[nt] = (f32x4){0.f, 0.f, 0.f, 0.f};
        #pragma unroll
        for (int kt = 0; kt < 4; ++kt) {
            short8 bF = *reinterpret_cast<const short8*>(&sW[nt * 16 + lr][kt * 32 + lg * 8]);
            c2[nt] = __builtin_amdgcn_mfma_f32_16x16x32_bf16(a2F[kt], bF, c2[nt], 0, 0, 0);
        }
        int col = nt * 16 + lr;
        b2v[nt] = b2[col]; gv[nt] = gamma[col]; bev[nt] = beta[col];
    }

    // LN stats per row (rows live in lane&15 groups)
    float rs[4] = {0.f, 0.f, 0.f, 0.f}, sq[4] = {0.f, 0.f, 0.f, 0.f};
    #pragma unroll
    for (int nt = 0; nt < 8; ++nt)
        #pragma unroll
        for (int reg = 0; reg < 4; ++reg) {
            float v = c2[nt][reg] + b2v[nt];
            rs[reg] += v; sq[reg] += v * v;
        }
    #pragma unroll
    for (int off = 1; off <= 8; off <<= 1)
        #pragma unroll
        for (int reg = 0; reg < 4; ++reg) {
            rs[reg] += __shfl_xor(rs[reg], off);
            sq[reg] += __shfl_xor(sq[reg], off);
        }
    float mu[4], rstd[4];
    #pragma unroll
    for (int reg = 0; reg < 4; ++reg) {
        mu[reg] = rs[reg] * (1.f / 128.f);
        float var = sq[reg] * (1.f / 128.f) - mu[reg] * mu[reg];
        rstd[reg] = rsqrtf(var + 1e-5f);
    }

    #pragma unroll
    for (int nt = 0; nt < 8; ++nt)
        #pragma unroll
        for (int reg = 0; reg < 4; ++reg) {
            int gr = node0 + mr + lg * 4 + reg;
            if (gr < n) {
                float v = c2[nt][reg] + b2v[nt];
                out[(size_t)gr * 128 + nt * 16 + lr] = gv[nt] * (v - mu[reg]) * rstd[reg] + bev[nt];
            }
        }
}

extern "C" void kernel_launch(void* const* d_in, const int* in_sizes, int n_in,
                              void* d_out, int out_size, void* d_ws, size_t ws_size,
                              hipStream_t stream) {
    const float* x     = (const float*)d_in[0];
    const int*   ei    = (const int*)d_in[1];
    const float* ew    = (const float*)d_in[2];
    const float* W1    = (const float*)d_in[3];
    const float* b1    = (const float*)d_in[4];
    const float* W2    = (const float*)d_in[5];
    const float* b2    = (const float*)d_in[6];
    const float* gamma = (const float*)d_in[7];
    const float* beta  = (const float*)d_in[8];

    int n = in_sizes[0] / D;
    int E = in_sizes[2];
    const int* src = ei;
    const int* tgt = ei + E;

    char* ws = (char*)d_ws;
    int2*     csr    = (int2*)ws;     ws += (size_t)E * sizeof(int2);
    unsigned* xb     = (unsigned*)ws; ws += (size_t)n * 64 * sizeof(unsigned);
    unsigned* cmb    = (unsigned*)ws; ws += (size_t)n * 64 * sizeof(unsigned);
    unsigned short* W1t = (unsigned short*)ws; ws += 128 * 128 * sizeof(unsigned short);
    unsigned short* W2t = (unsigned short*)ws; ws += 128 * 128 * sizeof(unsigned short);
    int*      deg    = (int*)ws;      ws += (size_t)n * sizeof(int);
    int*      rowptr = (int*)ws;      ws += ((size_t)n + 1) * sizeof(int);
    int*      cursor = (int*)ws;      ws += (size_t)n * sizeof(int);
    int*      part   = (int*)ws;      ws += (size_t)SCAN_T * sizeof(int);

    hipMemsetAsync((void*)deg, 0, (size_t)n * sizeof(int), stream);

    int nf4 = n * D / 4;
    k_prepx<<<(nf4 + 255) / 256, 256, 0, stream>>>(x, xb, nf4);
    k_prepw<<<64, 256, 0, stream>>>(W1, W2, W1t, W2t);

    k_hist<<<2048, 256, 0, stream>>>(tgt, deg, E);
    int nblk = (n + SCAN_CHUNK - 1) / SCAN_CHUNK;
    k_scan_local<<<nblk, SCAN_T, 0, stream>>>(deg, rowptr, part, n);
    k_scan_mid<<<1, SCAN_T, 0, stream>>>(part, nblk);
    k_scan_add<<<(n + 256) / 256, 256, 0, stream>>>(rowptr, cursor, part, n, E);
    k_reorder<<<2048, 256, 0, stream>>>(src, tgt, ew, cursor, csr, E);

    k_agg<<<(n + 3) / 4, 256, 0, stream>>>(rowptr, csr, x, xb, cmb, n);

    k_mlp<<<(n + 63) / 64, 256, 0, stream>>>(cmb, W1t, W2t, b1, b2, gamma, beta,
                                             (float*)d_out, n);
}

// Round 4
// 271.558 us; speedup vs baseline: 11.9335x; 1.2105x over previous
//
#include <hip/hip_runtime.h>
#include <hip/hip_bf16.h>

#define D 128
#define SCAN_T 256
#define SCAN_I 4
#define SCAN_CHUNK (SCAN_T * SCAN_I)

typedef __attribute__((ext_vector_type(8))) short short8;
typedef __attribute__((ext_vector_type(4))) float f32x4;

__device__ __forceinline__ unsigned short us_bf16(float f) {
    return __bfloat16_as_ushort(__float2bfloat16(f));
}
__device__ __forceinline__ unsigned pack_bf16(float a, float b) {
    return (unsigned)us_bf16(a) | ((unsigned)us_bf16(b) << 16);
}
__device__ __forceinline__ float bf_lo(unsigned v) { return __uint_as_float(v << 16); }
__device__ __forceinline__ float bf_hi(unsigned v) { return __uint_as_float(v & 0xffff0000u); }

// ---------- prep: x -> bf16 pairs; W -> bf16 transposed ----------
__global__ __launch_bounds__(256) void k_prepx(const float* __restrict__ x,
                                               unsigned* __restrict__ xb, int nf4) {
    int i = blockIdx.x * blockDim.x + threadIdx.x;
    if (i < nf4) {
        float4 v = reinterpret_cast<const float4*>(x)[i];
        uint2 o;
        o.x = pack_bf16(v.x, v.y);
        o.y = pack_bf16(v.z, v.w);
        reinterpret_cast<uint2*>(xb)[i] = o;
    }
}

__global__ __launch_bounds__(256) void k_prepw(const float* __restrict__ W1,
                                               const float* __restrict__ W2,
                                               unsigned short* __restrict__ W1t,
                                               unsigned short* __restrict__ W2t) {
    int idx = blockIdx.x * blockDim.x + threadIdx.x;   // 0..16383
    int k = idx >> 7, nn = idx & 127;
    W1t[nn * 128 + k] = us_bf16(W1[idx]);
    W2t[nn * 128 + k] = us_bf16(W2[idx]);
}

// ---------- CSR build ----------
__global__ __launch_bounds__(256) void k_hist(const int* __restrict__ tgt,
                                              int* __restrict__ deg, int E) {
    int i = blockIdx.x * blockDim.x + threadIdx.x;
    int stride = gridDim.x * blockDim.x;
    for (int e = i; e < E; e += stride) atomicAdd(&deg[tgt[e]], 1);
}

__global__ __launch_bounds__(SCAN_T) void k_scan_local(const int* __restrict__ deg,
                                                       int* __restrict__ rowptr,
                                                       int* __restrict__ part, int n) {
    __shared__ int sh[SCAN_T];
    int base = blockIdx.x * SCAN_CHUNK + threadIdx.x * SCAN_I;
    int v[SCAN_I]; int tsum = 0;
    #pragma unroll
    for (int k = 0; k < SCAN_I; ++k) { int idx = base + k; v[k] = (idx < n) ? deg[idx] : 0; tsum += v[k]; }
    sh[threadIdx.x] = tsum; __syncthreads();
    for (int off = 1; off < SCAN_T; off <<= 1) {
        int o = (threadIdx.x >= (unsigned)off) ? sh[threadIdx.x - off] : 0;
        __syncthreads();
        sh[threadIdx.x] += o;
        __syncthreads();
    }
    int excl = sh[threadIdx.x] - tsum;
    #pragma unroll
    for (int k = 0; k < SCAN_I; ++k) { int idx = base + k; if (idx < n) rowptr[idx] = excl; excl += v[k]; }
    if (threadIdx.x == 0) part[blockIdx.x] = sh[SCAN_T - 1];
}

__global__ __launch_bounds__(SCAN_T) void k_scan_mid(int* part, int nblk) {
    __shared__ int sh[SCAN_T];
    int v = (threadIdx.x < (unsigned)nblk) ? part[threadIdx.x] : 0;
    sh[threadIdx.x] = v; __syncthreads();
    for (int off = 1; off < SCAN_T; off <<= 1) {
        int o = (threadIdx.x >= (unsigned)off) ? sh[threadIdx.x - off] : 0;
        __syncthreads();
        sh[threadIdx.x] += o;
        __syncthreads();
    }
    if (threadIdx.x < (unsigned)nblk) part[threadIdx.x] = sh[threadIdx.x] - v;
}

__global__ __launch_bounds__(256) void k_scan_add(int* __restrict__ rowptr,
                                                  int* __restrict__ cursor,
                                                  const int* __restrict__ part, int n, int E) {
    int i = blockIdx.x * blockDim.x + threadIdx.x;
    if (i < n) { int r = rowptr[i] + part[i / SCAN_CHUNK]; rowptr[i] = r; cursor[i] = r; }
    if (i == n) rowptr[n] = E;
}

// XCD-sliced reorder: workgroup b handles only targets in slice (b & 7).
// Under round-robin block->XCD dispatch, each node's csr region is written by
// ONE XCD -> partial 64B lines merge in that XCD's L2 -> clean single writeback.
// (If the mapping assumption fails, result is still correct, only slower.)
__global__ __launch_bounds__(256) void k_reorder(const int* __restrict__ src,
                                                 const int* __restrict__ tgt,
                                                 const float* __restrict__ ew,
                                                 int* __restrict__ cursor,
                                                 int2* __restrict__ csr, int E, int sliceN) {
    int slice = blockIdx.x & 7;
    int lo = slice * sliceN, hi = lo + sliceN;
    int tpslice = (gridDim.x >> 3) * blockDim.x;
    int i = (blockIdx.x >> 3) * blockDim.x + threadIdx.x;
    for (int e = i; e < E; e += tpslice) {
        int t = tgt[e];
        if (t >= lo && t < hi) {
            int pos = atomicAdd(&cursor[t], 1);
            csr[pos] = make_int2(src[e], __float_as_int(ew[e]));
        }
    }
}

// ---------- aggregate: 1 wave per node; softmax + bf16 gather + sphere-norm ----------
__global__ __launch_bounds__(256) void k_agg(
    const int* __restrict__ rowptr, const int2* __restrict__ csr,
    const float* __restrict__ x, const unsigned* __restrict__ xb,
    unsigned* __restrict__ cmb, int n)
{
    int w = threadIdx.x >> 6;
    int lane = threadIdx.x & 63;
    int node = blockIdx.x * 4 + w;
    if (node >= n) node = n - 1;   // benign duplicate on tail

    int r0 = rowptr[node], r1 = rowptr[node + 1];

    // softmax max (lane-parallel over edges)
    float m = -INFINITY;
    for (int c = r0; c < r1; c += 64) {
        int e = c + lane;
        if (e < r1) m = fmaxf(m, __int_as_float(csr[e].y));
    }
    #pragma unroll
    for (int off = 32; off; off >>= 1) m = fmaxf(m, __shfl_xor(m, off));

    // softmax denom
    float s = 0.f;
    for (int c = r0; c < r1; c += 64) {
        int e = c + lane;
        if (e < r1) s += __expf(__int_as_float(csr[e].y) - m);
    }
    #pragma unroll
    for (int off = 32; off; off >>= 1) s += __shfl_xor(s, off);
    float inv = (s > 0.f) ? (1.f / s) : 0.f;

    // weighted gather: each lane owns dims {2*lane, 2*lane+1}
    float ax = 0.f, ay = 0.f;
    for (int c = r0; c < r1; c += 64) {
        int e = c + lane;
        int2 cr = (e < r1) ? csr[e] : make_int2(0, 0);
        float wn = (e < r1) ? __expf(__int_as_float(cr.y) - m) * inv : 0.f;
        int cnt = min(64, r1 - c);
        int j = 0;
        for (; j + 4 <= cnt; j += 4) {
            float w0 = __shfl(wn, j),     w1 = __shfl(wn, j + 1);
            float w2 = __shfl(wn, j + 2), w3 = __shfl(wn, j + 3);
            int  s0 = __shfl(cr.x, j),     s1 = __shfl(cr.x, j + 1);
            int  s2 = __shfl(cr.x, j + 2), s3 = __shfl(cr.x, j + 3);
            unsigned v0 = xb[(size_t)s0 * 64 + lane];
            unsigned v1 = xb[(size_t)s1 * 64 + lane];
            unsigned v2 = xb[(size_t)s2 * 64 + lane];
            unsigned v3 = xb[(size_t)s3 * 64 + lane];
            ax = fmaf(w0, bf_lo(v0), ax); ay = fmaf(w0, bf_hi(v0), ay);
            ax = fmaf(w1, bf_lo(v1), ax); ay = fmaf(w1, bf_hi(v1), ay);
            ax = fmaf(w2, bf_lo(v2), ax); ay = fmaf(w2, bf_hi(v2), ay);
            ax = fmaf(w3, bf_lo(v3), ax); ay = fmaf(w3, bf_hi(v3), ay);
        }
        for (; j < cnt; ++j) {
            float wj = __shfl(wn, j);
            int   sj = __shfl(cr.x, j);
            unsigned v = xb[(size_t)sj * 64 + lane];
            ax = fmaf(wj, bf_lo(v), ax);
            ay = fmaf(wj, bf_hi(v), ay);
        }
    }

    // projective average + combined = x + neigh
    float ss = ax * ax + ay * ay;
    #pragma unroll
    for (int off = 32; off; off >>= 1) ss += __shfl_xor(ss, off);
    float rn = 1.f / (sqrtf(ss) + 1e-9f);
    float2 xv = reinterpret_cast<const float2*>(x)[(size_t)node * 64 + lane];
    float cx = xv.x + ax * rn;
    float cy = xv.y + ay * rn;
    cmb[(size_t)node * 64 + lane] = pack_bf16(cx, cy);
}

// ---------- MLP + LN via MFMA: 64 nodes per block, 4 waves ----------
__global__ __launch_bounds__(256) void k_mlp(
    const unsigned* __restrict__ cmb,
    const unsigned short* __restrict__ W1t, const unsigned short* __restrict__ W2t,
    const float* __restrict__ b1, const float* __restrict__ b2,
    const float* __restrict__ gamma, const float* __restrict__ beta,
    float* __restrict__ out, int n)
{
    __shared__ __align__(16) unsigned short sA[64][136];
    __shared__ __align__(16) unsigned short sW[128][136];

    int node0 = blockIdx.x * 64;
    int w = threadIdx.x >> 6;
    int lane = threadIdx.x & 63;
    int lr = lane & 15;    // fragment row/col
    int lg = lane >> 4;    // k-group
    int mr = w * 16;       // this wave's row base in the tile

    // stage combined tile (bf16) and W1t
    for (int idx = threadIdx.x; idx < 64 * 16; idx += 256) {
        int row = idx >> 4, seg = idx & 15;
        int gr = node0 + row; if (gr >= n) gr = n - 1;
        uint4 v = reinterpret_cast<const uint4*>(cmb)[(size_t)gr * 16 + seg];
        *reinterpret_cast<uint4*>(&sA[row][seg * 8]) = v;
    }
    for (int idx = threadIdx.x; idx < 128 * 16; idx += 256) {
        int row = idx >> 4, seg = idx & 15;
        uint4 v = reinterpret_cast<const uint4*>(W1t)[row * 16 + seg];
        *reinterpret_cast<uint4*>(&sW[row][seg * 8]) = v;
    }
    __syncthreads();

    // GEMM1: h = relu(cmb @ W1 + b1), write back to sA as bf16
    short8 aF[4];
    #pragma unroll
    for (int kt = 0; kt < 4; ++kt)
        aF[kt] = *reinterpret_cast<const short8*>(&sA[mr + lr][kt * 32 + lg * 8]);

    #pragma unroll
    for (int nt = 0; nt < 8; ++nt) {
        f32x4 c = {0.f, 0.f, 0.f, 0.f};
        #pragma unroll
        for (int kt = 0; kt < 4; ++kt) {
            short8 bF = *reinterpret_cast<const short8*>(&sW[nt * 16 + lr][kt * 32 + lg * 8]);
            c = __builtin_amdgcn_mfma_f32_16x16x32_bf16(aF[kt], bF, c, 0, 0, 0);
        }
        float b1v = b1[nt * 16 + lr];
        #pragma unroll
        for (int reg = 0; reg < 4; ++reg) {
            float h = fmaxf(c[reg] + b1v, 0.f);
            sA[mr + lg * 4 + reg][nt * 16 + lr] = us_bf16(h);
        }
    }
    __syncthreads();

    // restage sW with W2t
    for (int idx = threadIdx.x; idx < 128 * 16; idx += 256) {
        int row = idx >> 4, seg = idx & 15;
        uint4 v = reinterpret_cast<const uint4*>(W2t)[row * 16 + seg];
        *reinterpret_cast<uint4*>(&sW[row][seg * 8]) = v;
    }
    __syncthreads();

    // GEMM2: a2 = h @ W2 + b2, then LayerNorm
    short8 a2F[4];
    #pragma unroll
    for (int kt = 0; kt < 4; ++kt)
        a2F[kt] = *reinterpret_cast<const short8*>(&sA[mr + lr][kt * 32 + lg * 8]);

    f32x4 c2[8];
    float b2v[8], gv[8], bev[8];
    #pragma unroll
    for (int nt = 0; nt < 8; ++nt) {
        c2[nt] = (f32x4){0.f, 0.f, 0.f, 0.f};
        #pragma unroll
        for (int kt = 0; kt < 4; ++kt) {
            short8 bF = *reinterpret_cast<const short8*>(&sW[nt * 16 + lr][kt * 32 + lg * 8]);
            c2[nt] = __builtin_amdgcn_mfma_f32_16x16x32_bf16(a2F[kt], bF, c2[nt], 0, 0, 0);
        }
        int col = nt * 16 + lr;
        b2v[nt] = b2[col]; gv[nt] = gamma[col]; bev[nt] = beta[col];
    }

    // LN stats per row (rows live in lane&15 groups)
    float rs[4] = {0.f, 0.f, 0.f, 0.f}, sq[4] = {0.f, 0.f, 0.f, 0.f};
    #pragma unroll
    for (int nt = 0; nt < 8; ++nt)
        #pragma unroll
        for (int reg = 0; reg < 4; ++reg) {
            float v = c2[nt][reg] + b2v[nt];
            rs[reg] += v; sq[reg] += v * v;
        }
    #pragma unroll
    for (int off = 1; off <= 8; off <<= 1)
        #pragma unroll
        for (int reg = 0; reg < 4; ++reg) {
            rs[reg] += __shfl_xor(rs[reg], off);
            sq[reg] += __shfl_xor(sq[reg], off);
        }
    float mu[4], rstd[4];
    #pragma unroll
    for (int reg = 0; reg < 4; ++reg) {
        mu[reg] = rs[reg] * (1.f / 128.f);
        float var = sq[reg] * (1.f / 128.f) - mu[reg] * mu[reg];
        rstd[reg] = rsqrtf(var + 1e-5f);
    }

    #pragma unroll
    for (int nt = 0; nt < 8; ++nt)
        #pragma unroll
        for (int reg = 0; reg < 4; ++reg) {
            int gr = node0 + mr + lg * 4 + reg;
            if (gr < n) {
                float v = c2[nt][reg] + b2v[nt];
                out[(size_t)gr * 128 + nt * 16 + lr] = gv[nt] * (v - mu[reg]) * rstd[reg] + bev[nt];
            }
        }
}

extern "C" void kernel_launch(void* const* d_in, const int* in_sizes, int n_in,
                              void* d_out, int out_size, void* d_ws, size_t ws_size,
                              hipStream_t stream) {
    const float* x     = (const float*)d_in[0];
    const int*   ei    = (const int*)d_in[1];
    const float* ew    = (const float*)d_in[2];
    const float* W1    = (const float*)d_in[3];
    const float* b1    = (const float*)d_in[4];
    const float* W2    = (const float*)d_in[5];
    const float* b2    = (const float*)d_in[6];
    const float* gamma = (const float*)d_in[7];
    const float* beta  = (const float*)d_in[8];

    int n = in_sizes[0] / D;
    int E = in_sizes[2];
    const int* src = ei;
    const int* tgt = ei + E;

    char* ws = (char*)d_ws;
    int2*     csr    = (int2*)ws;     ws += (size_t)E * sizeof(int2);
    unsigned* xb     = (unsigned*)ws; ws += (size_t)n * 64 * sizeof(unsigned);
    unsigned* cmb    = (unsigned*)ws; ws += (size_t)n * 64 * sizeof(unsigned);
    unsigned short* W1t = (unsigned short*)ws; ws += 128 * 128 * sizeof(unsigned short);
    unsigned short* W2t = (unsigned short*)ws; ws += 128 * 128 * sizeof(unsigned short);
    int*      deg    = (int*)ws;      ws += (size_t)n * sizeof(int);
    int*      rowptr = (int*)ws;      ws += ((size_t)n + 1) * sizeof(int);
    int*      cursor = (int*)ws;      ws += (size_t)n * sizeof(int);
    int*      part   = (int*)ws;      ws += (size_t)SCAN_T * sizeof(int);

    hipMemsetAsync((void*)deg, 0, (size_t)n * sizeof(int), stream);

    int nf4 = n * D / 4;
    k_prepx<<<(nf4 + 255) / 256, 256, 0, stream>>>(x, xb, nf4);
    k_prepw<<<64, 256, 0, stream>>>(W1, W2, W1t, W2t);

    k_hist<<<2048, 256, 0, stream>>>(tgt, deg, E);
    int nblk = (n + SCAN_CHUNK - 1) / SCAN_CHUNK;
    k_scan_local<<<nblk, SCAN_T, 0, stream>>>(deg, rowptr, part, n);
    k_scan_mid<<<1, SCAN_T, 0, stream>>>(part, nblk);
    k_scan_add<<<(n + 256) / 256, 256, 0, stream>>>(rowptr, cursor, part, n, E);

    int sliceN = (n + 7) / 8;
    k_reorder<<<2048, 256, 0, stream>>>(src, tgt, ew, cursor, csr, E, sliceN);

    k_agg<<<(n + 3) / 4, 256, 0, stream>>>(rowptr, csr, x, xb, cmb, n);

    k_mlp<<<(n + 63) / 64, 256, 0, stream>>>(cmb, W1t, W2t, b1, b2, gamma, beta,
                                             (float*)d_out, n);
}